// Round 10
// baseline (134.613 us; speedup 1.0000x reference)
//
#include <hip/hip_runtime.h>

// StericClashConstraint: N=16384 pts [N,3] fp32.
// out[0..3N-1] = pos passthrough; out[3N] = mean(max(1-dist,0), diag=0) * 0.02
//
// Round 10: x-sorted window prune (R9) with the pipeline actually deep enough.
// R9 stalled ~200 cyc/group on a 1-group-deep (4-load) prefetch: body 70 cyc
// < RTT. Now groups of 8 j's with full next-group prefetch (8 loads in
// flight, body ~200 cyc >= L1/L2 RTT) and SLICES=16/DSLICE=128 so busy waves
// run 16 fat groups (fixed per-wave latency chains amortized 4x; 4096 tasks =
// 1024 blocks = 4/CU, slice-tier mapping balances CUs).
// Window: e = cursor[bin+32] (start of bin+33) => all j>=e have dx>1. Pairs
// counted once (j>i sorted), doubled at end; diagonal structural (d>=1);
// out-of-window overshoot auto-zeros via fmax(1-sqrt(d2),0).

constexpr int   N       = 16384;
constexpr int   NBINS   = 2048;      // x in [-32,32), width 1/32
constexpr float BIN_LO  = -32.0f;
constexpr float BIN_INV = 32.0f;
constexpr int   PAD     = 16;        // sentinel tail (clamped loads land here)
constexpr int   IMAX    = N + PAD - 1;
constexpr int   WPB     = 4;         // waves per block
constexpr int   PBLOCKS = 1024;      // 4 blocks/CU exactly
constexpr int   SLICES  = 16;        // d-slices per 64-i batch
constexpr int   DSLICE  = 128;       // d's per slice (last slice unbounded)
constexpr int   BATCHES = N / 64;    // 256; tasks = 256*16 = 4096 = PBLOCKS*WPB
constexpr int   GRP     = 8;         // j's per pipelined group

// ws layout (bytes): [0]=acc f32, [4]=done u32, [64..64+8192)=hist u32[2048],
// [8320 ...)= sorted float4[N+PAD]

__global__ void prep_kernel(const float* __restrict__ pos, float* __restrict__ out,
                            unsigned int* __restrict__ hist, float4* __restrict__ srt) {
    const int t = blockIdx.x * blockDim.x + threadIdx.x;   // 0..16383
    if (t < (N * 3) / 4)
        reinterpret_cast<float4*>(out)[t] = reinterpret_cast<const float4*>(pos)[t];
    const float x = pos[3 * t];
    int bin = (int)floorf((x - BIN_LO) * BIN_INV);
    bin = min(max(bin, 0), NBINS - 1);
    atomicAdd(&hist[bin], 1u);
    if (t < PAD)                                           // sentinels: never violate
        srt[N + t] = make_float4(1.0e9f, 1.0e9f, 1.0e9f, 0.0f);
}

__global__ void scan_kernel(unsigned int* __restrict__ hist) {
    // one wave, barrier-free: lane handles 32 consecutive bins
    const int lane = threadIdx.x;                          // 0..63
    unsigned int v[32], tot = 0;
    #pragma unroll
    for (int k = 0; k < 32; ++k) { v[k] = hist[lane * 32 + k]; tot += v[k]; }
    unsigned int run = tot;                                // inclusive wave scan
    #pragma unroll
    for (int off = 1; off < 64; off <<= 1) {
        const unsigned int u = __shfl_up(run, off);
        if (lane >= off) run += u;
    }
    unsigned int excl = run - tot;                         // exclusive base
    #pragma unroll
    for (int k = 0; k < 32; ++k) { hist[lane * 32 + k] = excl; excl += v[k]; }
}

__global__ void scatter_kernel(const float* __restrict__ pos,
                               unsigned int* __restrict__ cursor,
                               float4* __restrict__ srt) {
    const int t = blockIdx.x * blockDim.x + threadIdx.x;   // 0..16383
    const float x = pos[3 * t], y = pos[3 * t + 1], z = pos[3 * t + 2];
    int bin = (int)floorf((x - BIN_LO) * BIN_INV);
    bin = min(max(bin, 0), NBINS - 1);
    const unsigned int dst = atomicAdd(&cursor[bin], 1u);
    srt[dst] = make_float4(x, y, z, 0.0f);
    // after this kernel, cursor[b] == start index of bin b+1
}

__device__ __forceinline__ float pair_term(const float4 pj, float xi, float yi, float zi) {
    const float dx = pj.x - xi, dy = pj.y - yi, dz = pj.z - zi;
    const float d2 = fmaf(dx, dx, fmaf(dy, dy, dz * dz));
    return fmaxf(1.0f - __builtin_amdgcn_sqrtf(d2), 0.0f); // auto-zero when far
}

__global__ void __launch_bounds__(256, 4)
pair_kernel(const float4* __restrict__ srt, const unsigned int* __restrict__ binEnd,
            float* __restrict__ out, float* __restrict__ acc,
            unsigned int* __restrict__ cnt) {
    __shared__ float wsum[WPB];
    const int lane  = threadIdx.x & 63;
    const int wv    = threadIdx.x >> 6;
    const int g     = blockIdx.x * WPB + wv;               // 0..4095
    const int batch = g & (BATCHES - 1);                   // fine-interleave batches
    const int slice = g >> 8;                              // tier spreads over CUs
    const int i     = (batch << 6) + lane;

    const float4 pi = srt[i];
    const float xi = pi.x, yi = pi.y, zi = pi.z;

    // window end: j >= e = cursor[bin+32] = start(bin+33)  =>  x_j - x_i > 1
    int bin = (int)floorf((xi - BIN_LO) * BIN_INV);
    bin = min(max(bin, 0), NBINS - 1);
    const int e = (int)binEnd[min(bin + 32, NBINS - 1)];
    int dmax = e - i;
    #pragma unroll
    for (int off = 32; off > 0; off >>= 1) dmax = max(dmax, __shfl_xor(dmax, off));
    const int dcap = dmax - 1;                             // largest d any lane needs
    const int dlo  = 1 + slice * DSLICE;

    float s = 0.0f;
    if (dlo <= dcap) {
        const int dhi    = (slice == SLICES - 1) ? dcap : min(dcap, dlo + DSLICE - 1);
        const int groups = (dhi - dlo + GRP) / GRP;        // overshoot auto-zeros
        int jb = i + dlo;
        float4 c[GRP];
        #pragma unroll
        for (int u = 0; u < GRP; ++u) c[u] = srt[min(jb + u, IMAX)];
        for (int gi = 0; gi < groups; ++gi) {
            float4 n[GRP];                                 // 8 loads in flight
            #pragma unroll
            for (int u = 0; u < GRP; ++u) n[u] = srt[min(jb + GRP + u, IMAX)];
            #pragma unroll
            for (int u = 0; u < GRP; ++u) s += pair_term(c[u], xi, yi, zi);
            #pragma unroll
            for (int u = 0; u < GRP; ++u) c[u] = n[u];
            jb += GRP;
        }
    }

    // reduce: wave shuffle -> LDS -> one atomic per block
    for (int off = 32; off > 0; off >>= 1) s += __shfl_down(s, off);
    if (lane == 0) wsum[wv] = s;
    __syncthreads();
    if (threadIdx.x == 0) {
        float bs = 0.0f;
        #pragma unroll
        for (int w = 0; w < WPB; ++w) bs += wsum[w];
        atomicAdd(acc, bs);
        __threadfence();
        const unsigned int done = atomicAdd(cnt, 1u);
        if (done == (unsigned int)(PBLOCKS - 1)) {         // last block finalizes
            __threadfence();
            const float total = atomicAdd(acc, 0.0f);      // device-coherent read
            const double mean = 2.0 * (double)total / ((double)N * (double)N);
            out[(size_t)N * 3] = (float)(mean * 0.02);
        }
    }
}

extern "C" void kernel_launch(void* const* d_in, const int* in_sizes, int n_in,
                              void* d_out, int out_size, void* d_ws, size_t ws_size,
                              hipStream_t stream) {
    const float* pos = (const float*)d_in[0];
    float* out = (float*)d_out;
    float*        acc  = (float*)d_ws;
    unsigned int* cnt  = (unsigned int*)d_ws + 1;
    unsigned int* hist = (unsigned int*)((char*)d_ws + 64);
    float4*       srt  = (float4*)((char*)d_ws + 8320);

    hipMemsetAsync(d_ws, 0, 64 + NBINS * 4, stream);       // acc, cnt, hist

    prep_kernel<<<N / 256, 256, 0, stream>>>(pos, out, hist, srt);
    scan_kernel<<<1, 64, 0, stream>>>(hist);
    scatter_kernel<<<N / 256, 256, 0, stream>>>(pos, hist, srt);
    pair_kernel<<<PBLOCKS, 256, 0, stream>>>(srt, hist, out, acc, cnt);
}

// Round 11
// 99.507 us; speedup vs baseline: 1.3528x; 1.3528x over previous
//
#include <hip/hip_runtime.h>

// StericClashConstraint: N=16384 pts [N,3] fp32.
// out[0..3N-1] = pos passthrough; out[3N] = mean(max(1-dist,0), diag=0) * 0.02
//
// Round 11: x-sorted window prune with LDS-staged windows. R8-R10 proved the
// compiler collapses any manual global-load pipeline (VGPR=36 vs the 64+ a
// real double-buffer needs -> s_waitcnt vmcnt(0) per group -> latency-bound
// at ~10% VALUBusy). Fix: convert latency to throughput. Each block = one
// 64-i batch x one 512-d tier; stages its j-window (576 float4 = 9 KB) into
// LDS once (flat streaming copy), then the inner loop is ds_read_b128 + VALU
// only — the pattern the compiler schedules near-optimally (fine lgkmcnt).
// LDS-pipe floor: 1.5e7 pairs x 16 B / 256 CU / 85 B/cyc ~ 4.6 us.
// Window from bin prefix table: e = cursor[bin+32] => all j>=e have dx>1.
// Pairs counted once (j>i sorted), doubled at end; diagonal structural (d>=1);
// overshoot auto-zeros via fmax(1-sqrt(d2),0); tier-3 has a (normally
// zero-trip) global fallback for d>2048 so correctness is data-independent.

constexpr int   N       = 16384;
constexpr int   NBINS   = 2048;      // x in [-32,32), width 1/32
constexpr float BIN_LO  = -32.0f;
constexpr float BIN_INV = 32.0f;
constexpr int   PAD     = 16;        // sentinel tail (clamped loads land here)
constexpr int   IMAX    = N + PAD - 1;
constexpr int   BATCHES = N / 64;    // 256
constexpr int   NTIERS  = 4;         // d-tiers per batch
constexpr int   TDSL    = 512;       // d's per tier (128 per wave)
constexpr int   PBLOCKS = BATCHES * NTIERS;   // 1024 = 4 blocks/CU
constexpr int   TILE    = TDSL + 64; // 576 float4 = 9 KB

// ws layout (bytes): [0]=acc f32, [4]=done u32, [64..64+8192)=hist u32[2048],
// [8320 ...)= sorted float4[N+PAD]

__global__ void prep_kernel(const float* __restrict__ pos, float* __restrict__ out,
                            unsigned int* __restrict__ hist, float4* __restrict__ srt) {
    const int t = blockIdx.x * blockDim.x + threadIdx.x;   // 0..16383
    if (t < (N * 3) / 4)
        reinterpret_cast<float4*>(out)[t] = reinterpret_cast<const float4*>(pos)[t];
    const float x = pos[3 * t];
    int bin = (int)floorf((x - BIN_LO) * BIN_INV);
    bin = min(max(bin, 0), NBINS - 1);
    atomicAdd(&hist[bin], 1u);
    if (t < PAD)                                           // sentinels: never violate
        srt[N + t] = make_float4(1.0e9f, 1.0e9f, 1.0e9f, 0.0f);
}

__global__ void scan_kernel(unsigned int* __restrict__ hist) {
    // one wave, barrier-free: lane handles 32 consecutive bins
    const int lane = threadIdx.x;                          // 0..63
    unsigned int v[32], tot = 0;
    #pragma unroll
    for (int k = 0; k < 32; ++k) { v[k] = hist[lane * 32 + k]; tot += v[k]; }
    unsigned int run = tot;                                // inclusive wave scan
    #pragma unroll
    for (int off = 1; off < 64; off <<= 1) {
        const unsigned int u = __shfl_up(run, off);
        if (lane >= off) run += u;
    }
    unsigned int excl = run - tot;                         // exclusive base
    #pragma unroll
    for (int k = 0; k < 32; ++k) { hist[lane * 32 + k] = excl; excl += v[k]; }
}

__global__ void scatter_kernel(const float* __restrict__ pos,
                               unsigned int* __restrict__ cursor,
                               float4* __restrict__ srt) {
    const int t = blockIdx.x * blockDim.x + threadIdx.x;   // 0..16383
    const float x = pos[3 * t], y = pos[3 * t + 1], z = pos[3 * t + 2];
    int bin = (int)floorf((x - BIN_LO) * BIN_INV);
    bin = min(max(bin, 0), NBINS - 1);
    const unsigned int dst = atomicAdd(&cursor[bin], 1u);
    srt[dst] = make_float4(x, y, z, 0.0f);
    // after this kernel, cursor[b] == start index of bin b+1 (window-end table)
}

__device__ __forceinline__ float pair_term(const float4 pj, float xi, float yi, float zi) {
    const float dx = pj.x - xi, dy = pj.y - yi, dz = pj.z - zi;
    const float d2 = fmaf(dx, dx, fmaf(dy, dy, dz * dz));
    return fmaxf(1.0f - __builtin_amdgcn_sqrtf(d2), 0.0f); // auto-zero when far
}

__global__ void __launch_bounds__(256, 4)
pair_kernel(const float4* __restrict__ srt, const unsigned int* __restrict__ binEnd,
            float* __restrict__ out, float* __restrict__ acc,
            unsigned int* __restrict__ cnt) {
    __shared__ float4 tile[TILE];
    __shared__ float  wsum[4];

    const int tid  = threadIdx.x;
    const int lane = tid & 63;
    const int wv   = tid >> 6;
    const int b     = blockIdx.x;
    const int batch = b & (BATCHES - 1);   // round-robins batches across XCDs
    const int tier  = b >> 8;
    const int i0    = batch << 6;
    const int i     = i0 + lane;

    const float4 pi = srt[i];
    const float xi = pi.x, yi = pi.y, zi = pi.z;

    // window end: j >= e = cursor[bin+32] = start(bin+33)  =>  x_j - x_i > 1
    int bin = (int)floorf((xi - BIN_LO) * BIN_INV);
    bin = min(max(bin, 0), NBINS - 1);
    const int e = (int)binEnd[min(bin + 32, NBINS - 1)];
    int dmax = e - i;                                      // >= 1 always
    #pragma unroll
    for (int off = 32; off > 0; off >>= 1) dmax = max(dmax, __shfl_xor(dmax, off));
    const int dcap = dmax - 1;                             // largest d any lane needs
    const int dlo  = 1 + tier * TDSL;

    float s = 0.0f;
    if (dlo <= dcap) {                                     // block-uniform branch
        // stage this tier's j-window: flat streaming copy (no dependent chain)
        const int jbase = i0 + dlo;
        #pragma unroll
        for (int u = tid; u < TILE; u += 256)
            tile[u] = srt[min(jbase + u, IMAX)];
        __syncthreads();

        const int wdlo = dlo + (wv << 7);                  // this wave's d start
        if (wdlo <= dcap) {                                // wave-uniform
            const int ddmax  = min(dcap, wdlo + 127) - wdlo;   // 0..127
            const int groups = (ddmax >> 3) + 1;           // 8-unroll, overshoot zeros
            int idx = (wv << 7) + lane;                    // tile index for dd=0
            for (int g = 0; g < groups; ++g) {
                #pragma unroll
                for (int u = 0; u < 8; ++u)
                    s += pair_term(tile[idx + u], xi, yi, zi);
                idx += 8;
            }
        }
    }

    // correctness fallback: d beyond the 4 tiers (2048) — zero-trip in practice
    if (tier == NTIERS - 1) {
        for (int d = NTIERS * TDSL + 1 + wv; d <= dcap; d += 4)
            s += pair_term(srt[min(i + d, IMAX)], xi, yi, zi);
    }

    // reduce: wave shuffle -> LDS -> one atomic per block
    for (int off = 32; off > 0; off >>= 1) s += __shfl_down(s, off);
    if (lane == 0) wsum[wv] = s;
    __syncthreads();
    if (tid == 0) {
        float bs = wsum[0] + wsum[1] + wsum[2] + wsum[3];
        atomicAdd(acc, bs);
        __threadfence();
        const unsigned int done = atomicAdd(cnt, 1u);
        if (done == (unsigned int)(PBLOCKS - 1)) {         // last block finalizes
            __threadfence();
            const float total = atomicAdd(acc, 0.0f);      // device-coherent read
            const double mean = 2.0 * (double)total / ((double)N * (double)N);
            out[(size_t)N * 3] = (float)(mean * 0.02);
        }
    }
}

extern "C" void kernel_launch(void* const* d_in, const int* in_sizes, int n_in,
                              void* d_out, int out_size, void* d_ws, size_t ws_size,
                              hipStream_t stream) {
    const float* pos = (const float*)d_in[0];
    float* out = (float*)d_out;
    float*        acc  = (float*)d_ws;
    unsigned int* cnt  = (unsigned int*)d_ws + 1;
    unsigned int* hist = (unsigned int*)((char*)d_ws + 64);
    float4*       srt  = (float4*)((char*)d_ws + 8320);

    hipMemsetAsync(d_ws, 0, 64 + NBINS * 4, stream);       // acc, cnt, hist

    prep_kernel<<<N / 256, 256, 0, stream>>>(pos, out, hist, srt);
    scan_kernel<<<1, 64, 0, stream>>>(hist);
    scatter_kernel<<<N / 256, 256, 0, stream>>>(pos, hist, srt);
    pair_kernel<<<PBLOCKS, 256, 0, stream>>>(srt, hist, out, acc, cnt);
}